// Round 10
// baseline (255.658 us; speedup 1.0000x reference)
//
#include <hip/hip_runtime.h>
#include <math.h>

#define NSITES 65536
#define WIN 8192
#define NW 8           // windows per sweep (schedule repeats across sweeps)
#define KN 8           // chunks (of 1024) per window
#define RMAX 64        // tracked rounds per window (observed depth ~13)
#define MAGIC 0x51bb5eed

// ws layout:
//   recpk  uint2[2*NSITES]   1048576 B  ({site, uniform-bits} per sorted slot, per sweep)
//   ends   int  [NW*RMAX]       2048 B  (cumulative round boundaries)
//   flags  int  [NW]              32 B  (MAGIC when window's schedule ready)

// wave-aggregated atomic rank: position for value v in counter array c
// (1-based values, v <= vmax; vmax wave-uniform).
__device__ __forceinline__ int agg_pos(int v, int* c, int vmax) {
  int pos = 0;
  const int lane = threadIdx.x & 63;
  for (int vv = 1; vv <= vmax; ++vv) {
    unsigned long long m = __ballot(v == vv);
    if (m) {
      int leader = __ffsll((long long)m) - 1;
      int base = 0;
      if (lane == leader) base = atomicAdd(&c[vv], (int)__popcll(m));
      base = __shfl(base, leader);
      if (v == vv) pos = base + (int)__popcll(m & ((1ull << lane) - 1ull));
    }
  }
  return pos;
}

__device__ __forceinline__ void do_update(unsigned char* cell,
                                          const unsigned int* cellw,
                                          const float* c0a, const float* c1a,
                                          const float* c2a, const float* c3a,
                                          unsigned uvv, float r) {
  const int u = uvv >> 8, v = (int)(uvv & 255u);
  const int um = u ? u - 1 : 0, up = u < 255 ? u + 1 : 255;
  const int vm = v ? v - 1 : 0, vp = v < 255 ? v + 1 : 255;
  const int cb = vm >> 2;              // dword col of 8-byte window start
  const int sh0 = (vm & 3) << 3;
  const int shv = (v - vm) << 3;       // 0 or 8
  const int shp = (vp - vm) << 3;      // 8 or 16 (or 8 at right border)
  int acc = 0;  // per-class counts in nibbles (class 4 -> bit16, unused)
  {  // top row: cols vm, v, vp (clipped dups included, matching reference)
    const unsigned int* rw = cellw + (um << 6) + cb;
    const unsigned long long wd =
        ((unsigned long long)rw[1] << 32) | (unsigned long long)rw[0];
    const unsigned wl = (unsigned)(wd >> sh0);
    acc += 1 << ((wl & 255u) << 2);
    acc += 1 << (((wl >> shv) & 255u) << 2);
    acc += 1 << (((wl >> shp) & 255u) << 2);
  }
  {  // middle row: cols vm, vp only (true center excluded exactly once)
    const unsigned int* rw = cellw + (u << 6) + cb;
    const unsigned long long wd =
        ((unsigned long long)rw[1] << 32) | (unsigned long long)rw[0];
    const unsigned wl = (unsigned)(wd >> sh0);
    acc += 1 << ((wl & 255u) << 2);
    acc += 1 << (((wl >> shp) & 255u) << 2);
  }
  {  // bottom row: cols vm, v, vp
    const unsigned int* rw = cellw + (up << 6) + cb;
    const unsigned long long wd =
        ((unsigned long long)rw[1] << 32) | (unsigned long long)rw[0];
    const unsigned wl = (unsigned)(wd >> sh0);
    acc += 1 << ((wl & 255u) << 2);
    acc += 1 << (((wl >> shv) & 255u) << 2);
    acc += 1 << (((wl >> shp) & 255u) << 2);
  }
  const int n0 = acc & 15, n1 = (acc >> 4) & 15, n2 = (acc >> 8) & 15;
  const int idx = n0 + 9 * n1 + 81 * n2;
  int cnt = (c0a[idx] < r) ? 1 : 0;
  cnt += (c1a[idx] < r) ? 1 : 0;
  cnt += (c2a[idx] < r) ? 1 : 0;
  cnt += (c3a[idx] < r) ? 1 : 0;
  cell[uvv] = (unsigned char)cnt;  // 0..4
}

// ---------------------------------------------------------------------------
// Fused kernel: block 0 = executor (consumer), blocks 1..8 = per-window
// schedulers (producers). Device-scope flag handshake per window.
// ---------------------------------------------------------------------------
__global__ __launch_bounds__(1024) void GibbsSampler_90443421319469_kernel(
    const int* __restrict__ Xi, const int* __restrict__ perm,
    const float* __restrict__ uni, const float* __restrict__ betap,
    uint2* __restrict__ recpk, int* __restrict__ ends, int* __restrict__ flags,
    int* __restrict__ out) {
#pragma clang fp contract(off)
  __shared__ __align__(16) unsigned char smem[147984];
  const int tid = threadIdx.x;

  if (blockIdx.x > 0) {
    // ================= producer: schedule window w =================
    const int w = blockIdx.x - 1;
    const int wbase = w * WIN;
    unsigned short* posg = (unsigned short*)smem;             // 128 KiB
    unsigned short* lvl = (unsigned short*)(smem + 131072);   // 16 KiB
    int* cnt = (int*)(smem + 147456);   // [65]
    int* coff = cnt + 65;               // [65]
    int* ctl = coff + 65;               // [0]=chg [1]=bmax

    for (int g = tid; g < NSITES / 8; g += 1024)
      ((uint4*)posg)[g] = make_uint4(0u, 0u, 0u, 0u);
    if (tid <= RMAX) { cnt[tid] = 0; coff[tid] = 0; }
    if (tid == 0) { ctl[0] = 0; ctl[1] = 0; }
    __syncthreads();

    for (int k = 0; k < KN; ++k) {
      const int lt = k * 1024 + tid;
      posg[perm[wbase + lt]] = (unsigned short)(lt + 1);  // sites unique/sweep
    }
    __syncthreads();

    // chunk-sequential leveling; earlier chunks final, intra-chunk preds in
    // two ulonglong shift-registers (no dynamically-indexed private arrays)
    for (int c = 0; c < KN; ++c) {
      const int lt = c * 1024 + tid;
      const int uv = perm[wbase + lt];
      const int u = uv >> 8, v = uv & 255;
      const int um = u ? u - 1 : 0, up = u < 255 ? u + 1 : 255;
      const int vm = v ? v - 1 : 0, vp = v < 255 ? v + 1 : 255;
      const int nb8[8] = {(um << 8) | vm, (um << 8) | v, (um << 8) | vp,
                          (u << 8) | vm,                 (u << 8) | vp,
                          (up << 8) | vm, (up << 8) | v, (up << 8) | vp};
      int basemax = 0;
      unsigned long long q0 = 0ull, q1 = 0ull;
      int nin = 0;
#pragma unroll
      for (int j = 0; j < 8; ++j) {
        const int p = posg[nb8[j]];  // clipped dup == self excluded by <
        if (p && p - 1 < lt) {
          if (p - 1 < c * 1024) basemax = max(basemax, (int)lvl[p - 1]);
          else {
            q1 = (q1 << 16) | (q0 >> 48);
            q0 = (q0 << 16) | (unsigned long long)(p - 1);
            ++nin;
          }
        }
      }
      int ml = basemax + 1;  // init from below (<= final level)
      lvl[lt] = (unsigned short)ml;
      __syncthreads();

      for (;;) {  // Jacobi micro-passes over intra-chunk chains (~6% nodes)
        if (tid == 0) ctl[0] = 0;
        __syncthreads();
        bool ch = false;
        if (nin) {
          int m = basemax;
#pragma unroll
          for (int i = 0; i < 8; ++i) {
            if (i < nin) {
              const unsigned pp =
                  (unsigned)((i < 4 ? (q0 >> (16 * i)) : (q1 >> (16 * (i - 4))))
                             & 0xFFFFull);
              m = max(m, (int)lvl[pp]);
            }
          }
          const int nl = m + 1;
          if (nl != ml) { ml = nl; lvl[lt] = (unsigned short)nl; ch = true; }
        }
        if (ch) ctl[0] = 1;
        __syncthreads();
        if (ctl[0] == 0) break;  // no-change pass == chunk converged
      }
    }

    {
      int mymax = 0;
#pragma unroll
      for (int k = 0; k < KN; ++k) mymax = max(mymax, (int)lvl[k * 1024 + tid]);
      atomicMax(&ctl[1], mymax);
    }
    __syncthreads();
    const int vmax = ctl[1];

#pragma unroll
    for (int k = 0; k < KN; ++k)
      (void)agg_pos((int)lvl[k * 1024 + tid], cnt, vmax);  // histogram
    __syncthreads();
    if (tid == 0) {
      int e = 0;
      for (int r = 0; r < RMAX; ++r) {  // cnt[0]==0
        coff[r] = e;
        e += cnt[r];
        ends[w * RMAX + r] = e;  // cumulative end through round r
      }
    }
    __syncthreads();  // posg reads done; safe to reuse as record staging

    uint2* srec = (uint2*)posg;  // 16384 uint2 = 128 KiB (both sweeps)
#pragma unroll
    for (int k = 0; k < KN; ++k) {
      const int lt = k * 1024 + tid;
      const int pos = agg_pos((int)lvl[lt], coff, vmax);
      const unsigned uvv = (unsigned)perm[wbase + lt];
      srec[pos] = make_uint2(uvv, __float_as_uint(uni[wbase + lt]));
      srec[WIN + pos] =
          make_uint2(uvv, __float_as_uint(uni[NSITES + wbase + lt]));
    }
    __syncthreads();

    const uint4* s4 = (const uint4*)srec;  // coalesced write-out
    uint4* d0 = (uint4*)(recpk + wbase);
    uint4* d1 = (uint4*)(recpk + NSITES + wbase);
    for (int g = tid; g < WIN / 2; g += 1024) {
      d0[g] = s4[g];
      d1[g] = s4[WIN / 2 + g];
    }
    __syncthreads();     // all stores issued & drained (barrier semantics)
    __threadfence();     // device-scope visibility (cross-XCD)
    if (tid == 0) atomicExch(&flags[w], MAGIC);  // release
    return;
  }

  // ================= consumer: executor (R8-proven structure) =============
  unsigned int* cellw = (unsigned int*)smem;              // 64 KiB lattice
  unsigned char* cell = (unsigned char*)smem;
  float* c0a = (float*)(smem + 65536);                    // 4 x 729 floats
  float* c1a = c0a + 729;
  float* c2a = c1a + 729;
  float* c3a = c2a + 729;
  int* lend = (int*)(smem + 65536 + 4 * 729 * 4);         // NW*RMAX ints
  const float beta = betap[0];

  for (int g = tid; g < NSITES / 4; g += 1024) {
    int4 x = ((const int4*)Xi)[g];
    cellw[g] = (unsigned)(x.x & 255) | ((unsigned)(x.y & 255) << 8) |
               ((unsigned)(x.z & 255) << 16) | ((unsigned)(x.w & 255) << 24);
  }
  // cumulative softmax table: bit-identical to per-update reference math
  for (int t = tid; t < 729; t += 1024) {
    const int n0 = t % 9, n1 = (t / 9) % 9, n2 = t / 81;
    const int n3 = 8 - n0 - n1 - n2;
    float v0 = 2.f, v1 = 2.f, v2 = 2.f, v3 = 2.f;  // unreachable combos
    if (n3 >= 0) {
      const int mx = max(max(n0, n1), max(n2, n3));
      const float xm = beta * (float)mx;   // fl(beta*mx), no FMA (contract off)
      const float x0 = beta * (float)n0;
      const float x1 = beta * (float)n1;
      const float x2 = beta * (float)n2;
      const float x3 = beta * (float)n3;
      const float e0 = (float)exp((double)(x0 - xm));
      const float e1 = (float)exp((double)(x1 - xm));
      const float e2 = (float)exp((double)(x2 - xm));
      const float e3 = (float)exp((double)(x3 - xm));
      const float s = ((e0 + e1) + e2) + e3;  // sequential sum, like np/XLA
      v0 = e0 / s;                            // IEEE f32 divides, like ref
      v1 = v0 + e1 / s;
      v2 = v1 + e2 / s;
      v3 = v2 + e3 / s;
    }
    c0a[t] = v0; c1a[t] = v1; c2a[t] = v2; c3a[t] = v3;
  }
  __syncthreads();

  for (int w = 0; w < 2 * NW; ++w) {
    const int ww = w & (NW - 1);
    const int sw = w >> 3;  // sweep index (NW==8)

    if (w < NW) {  // gate on this window's schedule (first sweep only)
      if (tid == 0) {
        while (atomicAdd(&flags[ww], 0) != MAGIC) __builtin_amdgcn_s_sleep(8);
      }
      __syncthreads();
      __threadfence();  // acquire: invalidate stale cached lines
      if (tid < RMAX) lend[ww * RMAX + tid] = ends[ww * RMAX + tid];
      __syncthreads();
    }

    const uint2* rp = recpk + sw * NSITES + ww * WIN;
    const int* le = &lend[ww * RMAX];

    int nb = 0, ne = le[1];
    uint2 cur = make_uint2(0u, 0u);
    if (tid < ne) cur = rp[tid];  // round-1 first-iteration record

    for (int rd = 1; rd < RMAX; ++rd) {
      const int b = nb, e = ne;
      if (b >= WIN) break;  // uniform: window complete

      if (WIN - b <= 64) {
        // -------- single-wave tail: no block barriers between rounds ------
        if (tid < 64) {
          const int i = b + tid;
          int myrd = 0;
          uint2 rc = make_uint2(0u, 0u);
          if (i < WIN) {
            myrd = rd;
            while (le[myrd] <= i) ++myrd;  // le monotone, reaches WIN
            rc = rp[i];
          }
          int mx = myrd;
#pragma unroll
          for (int off = 1; off < 64; off <<= 1)
            mx = max(mx, __shfl_xor(mx, off));
          for (int rr = rd; rr <= mx; ++rr) {
            // intra-wave LDS ordering: ds ops issue in order; compiler adds
            // lgkmcnt waits for the cell write->read dependences
            if (myrd == rr)
              do_update(cell, cellw, c0a, c1a, c2a, c3a, rc.x,
                        __uint_as_float(rc.y));
          }
        }
        __syncthreads();
        break;  // window complete
      }

      nb = e;
      ne = (rd + 1 < RMAX) ? le[rd + 1] : e;
      // prefetch next round's first-iter record (read-only stream)
      uint2 nxt = make_uint2(0u, 0u);
      if (nb + tid < ne) nxt = rp[nb + tid];
      // execute current round
      if (b + tid < e)
        do_update(cell, cellw, c0a, c1a, c2a, c3a, cur.x,
                  __uint_as_float(cur.y));
      for (int i = b + tid + 1024; i < e; i += 1024) {
        const uint2 rc = rp[i];
        do_update(cell, cellw, c0a, c1a, c2a, c3a, rc.x,
                  __uint_as_float(rc.y));
      }
      __syncthreads();  // round rd writes before round rd+1 reads
      cur = nxt;
    }
  }

  for (int g = tid; g < NSITES / 4; g += 1024) {
    const unsigned p = cellw[g];
    int4 o;
    o.x = (int)(p & 255u);
    o.y = (int)((p >> 8) & 255u);
    o.z = (int)((p >> 16) & 255u);
    o.w = (int)((p >> 24) & 255u);
    ((int4*)out)[g] = o;
  }
}

extern "C" void kernel_launch(void* const* d_in, const int* in_sizes, int n_in,
                              void* d_out, int out_size, void* d_ws,
                              size_t ws_size, hipStream_t stream) {
  const int* Xi = (const int*)d_in[0];
  const int* perm = (const int*)d_in[1];
  const float* uni = (const float*)d_in[2];
  const float* beta = (const float*)d_in[3];
  int* out = (int*)d_out;

  char* ws = (char*)d_ws;
  uint2* recpk = (uint2*)ws;                    // 1 MiB
  int* ends = (int*)(ws + 2 * NSITES * 8);      // 2 KiB
  int* flags = (int*)(ws + 2 * NSITES * 8 + 2048);  // 32 B

  GibbsSampler_90443421319469_kernel<<<dim3(NW + 1), dim3(1024), 0, stream>>>(
      Xi, perm, uni, beta, recpk, ends, flags, out);
}

// Round 11
// 254.676 us; speedup vs baseline: 1.0039x; 1.0039x over previous
//
#include <hip/hip_runtime.h>
#include <math.h>

#define NSITES 65536
#define WIN 8192
#define NW 8           // windows per sweep (schedule repeats across sweeps)
#define KN 8           // chunks (of 1024) per window
#define RMAX 64        // tracked rounds per window (observed depth ~13)
#define MAGIC 0x51bb5eed

// ws layout:
//   recpk  uint2[2*NSITES]   1048576 B  ({site, uniform-bits} per sorted slot, per sweep)
//   ends   int  [NW*RMAX]       2048 B  (cumulative round boundaries)
//   flags  int  [NW]              32 B  (MAGIC when window's schedule ready)

// wave-aggregated atomic rank: position for value v in counter array c
// (1-based values, v <= vmax; vmax wave-uniform).
__device__ __forceinline__ int agg_pos(int v, int* c, int vmax) {
  int pos = 0;
  const int lane = threadIdx.x & 63;
  for (int vv = 1; vv <= vmax; ++vv) {
    unsigned long long m = __ballot(v == vv);
    if (m) {
      int leader = __ffsll((long long)m) - 1;
      int base = 0;
      if (lane == leader) base = atomicAdd(&c[vv], (int)__popcll(m));
      base = __shfl(base, leader);
      if (v == vv) pos = base + (int)__popcll(m & ((1ull << lane) - 1ull));
    }
  }
  return pos;
}

__device__ __forceinline__ void do_update(unsigned char* cell,
                                          const unsigned int* cellw,
                                          const float* c0a, const float* c1a,
                                          const float* c2a, const float* c3a,
                                          unsigned uvv, float r) {
  const int u = uvv >> 8, v = (int)(uvv & 255u);
  const int um = u ? u - 1 : 0, up = u < 255 ? u + 1 : 255;
  const int vm = v ? v - 1 : 0, vp = v < 255 ? v + 1 : 255;
  const int cb = vm >> 2;              // dword col of 8-byte window start
  const int sh0 = (vm & 3) << 3;
  const int shv = (v - vm) << 3;       // 0 or 8
  const int shp = (vp - vm) << 3;      // 8 or 16 (or 8 at right border)
  int acc = 0;  // per-class counts in nibbles (class 4 -> bit16, unused)
  {  // top row: cols vm, v, vp (clipped dups included, matching reference)
    const unsigned int* rw = cellw + (um << 6) + cb;
    const unsigned long long wd =
        ((unsigned long long)rw[1] << 32) | (unsigned long long)rw[0];
    const unsigned wl = (unsigned)(wd >> sh0);
    acc += 1 << ((wl & 255u) << 2);
    acc += 1 << (((wl >> shv) & 255u) << 2);
    acc += 1 << (((wl >> shp) & 255u) << 2);
  }
  {  // middle row: cols vm, vp only (true center excluded exactly once)
    const unsigned int* rw = cellw + (u << 6) + cb;
    const unsigned long long wd =
        ((unsigned long long)rw[1] << 32) | (unsigned long long)rw[0];
    const unsigned wl = (unsigned)(wd >> sh0);
    acc += 1 << ((wl & 255u) << 2);
    acc += 1 << (((wl >> shp) & 255u) << 2);
  }
  {  // bottom row: cols vm, v, vp
    const unsigned int* rw = cellw + (up << 6) + cb;
    const unsigned long long wd =
        ((unsigned long long)rw[1] << 32) | (unsigned long long)rw[0];
    const unsigned wl = (unsigned)(wd >> sh0);
    acc += 1 << ((wl & 255u) << 2);
    acc += 1 << (((wl >> shv) & 255u) << 2);
    acc += 1 << (((wl >> shp) & 255u) << 2);
  }
  const int n0 = acc & 15, n1 = (acc >> 4) & 15, n2 = (acc >> 8) & 15;
  const int idx = n0 + 9 * n1 + 81 * n2;
  int cnt = (c0a[idx] < r) ? 1 : 0;
  cnt += (c1a[idx] < r) ? 1 : 0;
  cnt += (c2a[idx] < r) ? 1 : 0;
  cnt += (c3a[idx] < r) ? 1 : 0;
  cell[uvv] = (unsigned char)cnt;  // 0..4
}

// ---------------------------------------------------------------------------
// Fused kernel: block 0 = executor (consumer), blocks 1..8 = per-window
// schedulers (producers). Device-scope flag handshake per window.
// ---------------------------------------------------------------------------
__global__ __launch_bounds__(1024) void GibbsSampler_90443421319469_kernel(
    const int* __restrict__ Xi, const int* __restrict__ perm,
    const float* __restrict__ uni, const float* __restrict__ betap,
    uint2* __restrict__ recpk, int* __restrict__ ends, int* __restrict__ flags,
    int* __restrict__ out) {
#pragma clang fp contract(off)
  __shared__ __align__(16) unsigned char smem[148240];
  const int tid = threadIdx.x;

  if (blockIdx.x > 0) {
    // ================= producer: schedule window w =================
    const int w = blockIdx.x - 1;
    const int wbase = w * WIN;
    unsigned short* posg = (unsigned short*)smem;            // 128 KiB
    unsigned short* lvl = (unsigned short*)(smem + 131072);  // 16 KiB
    int* cnt = (int*)(smem + 147456);  // [65]
    int* coff = cnt + 65;              // [65]
    int* ctl = coff + 65;              // [2]: [0]=bmax
    int* chgar = ctl + 2;              // [64] pass-indexed change flags

    for (int g = tid; g < NSITES / 8; g += 1024)
      ((uint4*)posg)[g] = make_uint4(0u, 0u, 0u, 0u);
    ((uint4*)lvl)[tid] = make_uint4(0u, 0u, 0u, 0u);  // pre-zero: WIN/8==1024
    if (tid <= RMAX) { cnt[tid] = 0; coff[tid] = 0; }
    if (tid < 64) chgar[tid] = 0;
    if (tid == 0) ctl[0] = 0;
    __syncthreads();

    int uvk[KN];
#pragma unroll
    for (int k = 0; k < KN; ++k) {
      const int lt = k * 1024 + tid;
      uvk[k] = perm[wbase + lt];
      posg[uvk[k]] = (unsigned short)(lt + 1);  // sites unique within a sweep
    }
    __syncthreads();

    // Pass A: chunk-sequential warm start. lvl pre-zeroed, so unresolved
    // (intra-chunk) preds read 0 -> a safe lower bound; monotone Jacobi
    // from below converges to the same unique least fixpoint.
    unsigned long long q0[KN], q1[KN];  // up to 8 pred positions, 16b each
    int nin[KN], ml[KN];
#pragma unroll
    for (int c = 0; c < KN; ++c) {
      const int lt = c * 1024 + tid;
      const int uv = uvk[c], u = uv >> 8, v = uv & 255;
      const int um = u ? u - 1 : 0, up = u < 255 ? u + 1 : 255;
      const int vm = v ? v - 1 : 0, vp = v < 255 ? v + 1 : 255;
      const int nb8[8] = {(um << 8) | vm, (um << 8) | v, (um << 8) | vp,
                          (u << 8) | vm,                 (u << 8) | vp,
                          (up << 8) | vm, (up << 8) | v, (up << 8) | vp};
      unsigned long long a0 = 0ull, a1 = 0ull;
      int nn = 0, bm = 0;
#pragma unroll
      for (int j = 0; j < 8; ++j) {
        const int p = posg[nb8[j]];  // clipped dup == self excluded by <
        if (p && p - 1 < lt) {
          a1 = (a1 << 16) | (a0 >> 48);
          a0 = (a0 << 16) | (unsigned long long)(p - 1);
          ++nn;
          bm = max(bm, (int)lvl[p - 1]);  // 0 if not yet written (lower bound)
        }
      }
      q0[c] = a0; q1[c] = a1; nin[c] = nn;
      ml[c] = bm + 1;
      lvl[lt] = (unsigned short)ml[c];
      __syncthreads();  // publish chunk c before chunk c+1's reads
    }

    // chaotic sparse Jacobi: only nodes with preds recompute; one barrier
    // per pass via pass-indexed change flags (no reset barrier).
    for (int pass = 0; pass < 63; ++pass) {
      bool ch = false;
#pragma unroll
      for (int c = 0; c < KN; ++c) {
        if (nin[c]) {
          int m = 0;
#pragma unroll
          for (int i = 0; i < 8; ++i) {
            if (i < nin[c]) {
              const unsigned pp =
                  (unsigned)((i < 4 ? (q0[c] >> (16 * i))
                                    : (q1[c] >> (16 * (i - 4)))) & 0xFFFFull);
              m = max(m, (int)lvl[pp]);
            }
          }
          const int nl = m + 1;  // monotone: nl >= ml[c]
          if (nl != ml[c]) {
            ml[c] = nl;
            lvl[c * 1024 + tid] = (unsigned short)nl;
            ch = true;
          }
        }
      }
      if (ch) chgar[pass] = 1;
      __syncthreads();
      if (chgar[pass] == 0) break;  // no-change pass == least fixpoint
    }

    {
      int mym = 0;
#pragma unroll
      for (int k = 0; k < KN; ++k) mym = max(mym, ml[k]);
      atomicMax(&ctl[0], mym);
    }
    __syncthreads();
    const int vmax = ctl[0];

#pragma unroll
    for (int k = 0; k < KN; ++k) (void)agg_pos(ml[k], cnt, vmax);  // histogram
    __syncthreads();
    if (tid == 0) {
      int e = 0;
      for (int r = 0; r < RMAX; ++r) {  // cnt[0]==0
        coff[r] = e;
        e += cnt[r];
        ends[w * RMAX + r] = e;  // cumulative end through round r
      }
    }
    __syncthreads();  // posg reads all done; reuse as record staging

    uint2* srec = (uint2*)posg;  // 16384 uint2 = 128 KiB (both sweeps)
#pragma unroll
    for (int k = 0; k < KN; ++k) {
      const int lt = k * 1024 + tid;
      const int pos = agg_pos(ml[k], coff, vmax);
      const unsigned uvv = (unsigned)uvk[k];
      srec[pos] = make_uint2(uvv, __float_as_uint(uni[wbase + lt]));
      srec[WIN + pos] =
          make_uint2(uvv, __float_as_uint(uni[NSITES + wbase + lt]));
    }
    __syncthreads();

    const uint4* s4 = (const uint4*)srec;  // coalesced write-out
    uint4* d0 = (uint4*)(recpk + wbase);
    uint4* d1 = (uint4*)(recpk + NSITES + wbase);
    for (int g = tid; g < WIN / 2; g += 1024) {
      d0[g] = s4[g];
      d1[g] = s4[WIN / 2 + g];
    }
    __syncthreads();     // all stores issued & drained (barrier semantics)
    __threadfence();     // device-scope visibility (cross-XCD)
    if (tid == 0) atomicExch(&flags[w], MAGIC);  // release
    return;
  }

  // ================= consumer: executor (R8-proven structure) =============
  unsigned int* cellw = (unsigned int*)smem;  // 64 KiB lattice
  unsigned char* cell = (unsigned char*)smem;
  float* c0a = (float*)(smem + 65536);        // 4 x 729 floats
  float* c1a = c0a + 729;
  float* c2a = c1a + 729;
  float* c3a = c2a + 729;
  int* lend = (int*)(smem + 65536 + 4 * 729 * 4);  // NW*RMAX ints
  const float beta = betap[0];

  for (int g = tid; g < NSITES / 4; g += 1024) {
    int4 x = ((const int4*)Xi)[g];
    cellw[g] = (unsigned)(x.x & 255) | ((unsigned)(x.y & 255) << 8) |
               ((unsigned)(x.z & 255) << 16) | ((unsigned)(x.w & 255) << 24);
  }
  // cumulative softmax table: bit-identical to per-update reference math
  for (int t = tid; t < 729; t += 1024) {
    const int n0 = t % 9, n1 = (t / 9) % 9, n2 = t / 81;
    const int n3 = 8 - n0 - n1 - n2;
    float v0 = 2.f, v1 = 2.f, v2 = 2.f, v3 = 2.f;  // unreachable combos
    if (n3 >= 0) {
      const int mx = max(max(n0, n1), max(n2, n3));
      const float xm = beta * (float)mx;   // fl(beta*mx), no FMA (contract off)
      const float x0 = beta * (float)n0;
      const float x1 = beta * (float)n1;
      const float x2 = beta * (float)n2;
      const float x3 = beta * (float)n3;
      const float e0 = (float)exp((double)(x0 - xm));
      const float e1 = (float)exp((double)(x1 - xm));
      const float e2 = (float)exp((double)(x2 - xm));
      const float e3 = (float)exp((double)(x3 - xm));
      const float s = ((e0 + e1) + e2) + e3;  // sequential sum, like np/XLA
      v0 = e0 / s;                            // IEEE f32 divides, like ref
      v1 = v0 + e1 / s;
      v2 = v1 + e2 / s;
      v3 = v2 + e3 / s;
    }
    c0a[t] = v0; c1a[t] = v1; c2a[t] = v2; c3a[t] = v3;
  }
  __syncthreads();

  for (int w = 0; w < 2 * NW; ++w) {
    const int ww = w & (NW - 1);
    const int sw = w >> 3;  // sweep index (NW==8)

    if (w < NW) {  // gate on this window's schedule (first sweep only)
      if (tid == 0) {
        while (atomicAdd(&flags[ww], 0) != MAGIC) __builtin_amdgcn_s_sleep(8);
      }
      __syncthreads();
      __threadfence();  // acquire: invalidate stale cached lines
      if (tid < RMAX) lend[ww * RMAX + tid] = ends[ww * RMAX + tid];
      __syncthreads();
    }

    const uint2* rp = recpk + sw * NSITES + ww * WIN;
    const int* le = &lend[ww * RMAX];

    int nb = 0, ne = le[1];
    uint2 cur = make_uint2(0u, 0u);
    if (tid < ne) cur = rp[tid];  // round-1 first-iteration record

    for (int rd = 1; rd < RMAX; ++rd) {
      const int b = nb, e = ne;
      if (b >= WIN) break;  // uniform: window complete

      if (WIN - b <= 64) {
        // -------- single-wave tail: no block barriers between rounds ------
        if (tid < 64) {
          const int i = b + tid;
          int myrd = 0;
          uint2 rc = make_uint2(0u, 0u);
          if (i < WIN) {
            myrd = rd;
            while (le[myrd] <= i) ++myrd;  // le monotone, reaches WIN
            rc = rp[i];
          }
          int mx = myrd;
#pragma unroll
          for (int off = 1; off < 64; off <<= 1)
            mx = max(mx, __shfl_xor(mx, off));
          for (int rr = rd; rr <= mx; ++rr) {
            // intra-wave LDS ordering: ds ops issue in order; compiler adds
            // lgkmcnt waits for the cell write->read dependences
            if (myrd == rr)
              do_update(cell, cellw, c0a, c1a, c2a, c3a, rc.x,
                        __uint_as_float(rc.y));
          }
        }
        __syncthreads();
        break;  // window complete
      }

      nb = e;
      ne = (rd + 1 < RMAX) ? le[rd + 1] : e;
      // prefetch next round's first-iter record (read-only stream)
      uint2 nxt = make_uint2(0u, 0u);
      if (nb + tid < ne) nxt = rp[nb + tid];
      // execute current round
      if (b + tid < e)
        do_update(cell, cellw, c0a, c1a, c2a, c3a, cur.x,
                  __uint_as_float(cur.y));
      for (int i = b + tid + 1024; i < e; i += 1024) {
        const uint2 rc = rp[i];
        do_update(cell, cellw, c0a, c1a, c2a, c3a, rc.x,
                  __uint_as_float(rc.y));
      }
      __syncthreads();  // round rd writes before round rd+1 reads
      cur = nxt;
    }
  }

  for (int g = tid; g < NSITES / 4; g += 1024) {
    const unsigned p = cellw[g];
    int4 o;
    o.x = (int)(p & 255u);
    o.y = (int)((p >> 8) & 255u);
    o.z = (int)((p >> 16) & 255u);
    o.w = (int)((p >> 24) & 255u);
    ((int4*)out)[g] = o;
  }
}

extern "C" void kernel_launch(void* const* d_in, const int* in_sizes, int n_in,
                              void* d_out, int out_size, void* d_ws,
                              size_t ws_size, hipStream_t stream) {
  const int* Xi = (const int*)d_in[0];
  const int* perm = (const int*)d_in[1];
  const float* uni = (const float*)d_in[2];
  const float* beta = (const float*)d_in[3];
  int* out = (int*)d_out;

  char* ws = (char*)d_ws;
  uint2* recpk = (uint2*)ws;                        // 1 MiB
  int* ends = (int*)(ws + 2 * NSITES * 8);          // 2 KiB
  int* flags = (int*)(ws + 2 * NSITES * 8 + 2048);  // 32 B

  GibbsSampler_90443421319469_kernel<<<dim3(NW + 1), dim3(1024), 0, stream>>>(
      Xi, perm, uni, beta, recpk, ends, flags, out);
}